// Round 1
// baseline (451.102 us; speedup 1.0000x reference)
//
#include <hip/hip_runtime.h>

// Salt & pepper noise application:
//   out = (u < 0.01f) ? 0.0f : (u < 0.02f) ? 1.0f : img
// Pure elementwise, memory-bound. N = 64*3*512*512 = 50,331,648 (divisible by 4).
// Traffic: 2 fp32 reads + 1 fp32 write = ~604 MB -> roofline ~96 us @ 6.3 TB/s.

#define HALF_T 0.01f
#define FULL_T 0.02f

__global__ __launch_bounds__(256) void saltpepper_kernel(
    const float4* __restrict__ img,
    const float4* __restrict__ u,
    float4* __restrict__ out,
    int n4)
{
    int idx = blockIdx.x * blockDim.x + threadIdx.x;
    int stride = gridDim.x * blockDim.x;
    for (int i = idx; i < n4; i += stride) {
        float4 iv = img[i];
        float4 uv = u[i];
        float4 ov;
        ov.x = (uv.x < HALF_T) ? 0.0f : (uv.x < FULL_T) ? 1.0f : iv.x;
        ov.y = (uv.y < HALF_T) ? 0.0f : (uv.y < FULL_T) ? 1.0f : iv.y;
        ov.z = (uv.z < HALF_T) ? 0.0f : (uv.z < FULL_T) ? 1.0f : iv.z;
        ov.w = (uv.w < HALF_T) ? 0.0f : (uv.w < FULL_T) ? 1.0f : iv.w;
        out[i] = ov;
    }
}

// Scalar tail kernel (defensive; n is divisible by 4 for this problem so it
// launches with 0 blocks and is skipped).
__global__ __launch_bounds__(256) void saltpepper_tail_kernel(
    const float* __restrict__ img,
    const float* __restrict__ u,
    float* __restrict__ out,
    int start, int n)
{
    int i = start + blockIdx.x * blockDim.x + threadIdx.x;
    if (i < n) {
        float uv = u[i];
        out[i] = (uv < HALF_T) ? 0.0f : (uv < FULL_T) ? 1.0f : img[i];
    }
}

extern "C" void kernel_launch(void* const* d_in, const int* in_sizes, int n_in,
                              void* d_out, int out_size, void* d_ws, size_t ws_size,
                              hipStream_t stream) {
    const float* img = (const float*)d_in[0];
    const float* u   = (const float*)d_in[1];
    float* out = (float*)d_out;
    int n = in_sizes[0];

    int n4 = n / 4;
    int tail_start = n4 * 4;

    const int block = 256;
    // Enough blocks for full occupancy with a short grid-stride loop:
    // 256 CUs * ~8 blocks/CU = 2048; cap at what's needed.
    int grid = (n4 + block - 1) / block;
    const int max_grid = 256 * 16;
    if (grid > max_grid) grid = max_grid;

    if (n4 > 0) {
        saltpepper_kernel<<<grid, block, 0, stream>>>(
            (const float4*)img, (const float4*)u, (float4*)out, n4);
    }

    int tail = n - tail_start;
    if (tail > 0) {
        int tgrid = (tail + block - 1) / block;
        saltpepper_tail_kernel<<<tgrid, block, 0, stream>>>(
            img, u, out, tail_start, n);
    }
}

// Round 3
// 450.574 us; speedup vs baseline: 1.0012x; 1.0012x over previous
//
#include <hip/hip_runtime.h>

// Salt & pepper: out = (u < 0.01) ? 0 : (u < 0.02) ? 1 : img
// N = 64*3*512*512 = 50,331,648 fp32 (n4 = 12,582,912 float4s, divisible by 1024).
//
// Round 1 post-mortem: 158 us/dispatch @ 2.5 TB/s, VGPR_Count=8 -> the
// grid-stride loop was register-starved: one load in flight per wave,
// vmcnt(0) drain per iteration => MLP-bound, not BW-bound.
// Round 2: compile fail — __builtin_nontemporal_store rejects HIP float4
// (struct-wrapped). Round 3: native ext_vector_type(4) float vector, which
// the builtin accepts; otherwise identical plan: 4 vec4s/thread, all 8
// loads issued independently before use, nontemporal stores.

#define HALF_T 0.01f
#define FULL_T 0.02f

typedef float floatx4 __attribute__((ext_vector_type(4)));

__device__ __forceinline__ floatx4 sp_select(floatx4 uv, floatx4 iv) {
    floatx4 ov;
    ov.x = (uv.x < HALF_T) ? 0.0f : (uv.x < FULL_T) ? 1.0f : iv.x;
    ov.y = (uv.y < HALF_T) ? 0.0f : (uv.y < FULL_T) ? 1.0f : iv.y;
    ov.z = (uv.z < HALF_T) ? 0.0f : (uv.z < FULL_T) ? 1.0f : iv.z;
    ov.w = (uv.w < HALF_T) ? 0.0f : (uv.w < FULL_T) ? 1.0f : iv.w;
    return ov;
}

// Main kernel: each block covers 4*256 = 1024 consecutive float4s.
// Thread t handles indices base+t, base+t+256, base+t+512, base+t+768 —
// every one of the 4 load/store steps is fully wave-coalesced.
__global__ __launch_bounds__(256) void saltpepper_x4_kernel(
    const floatx4* __restrict__ img,
    const floatx4* __restrict__ u,
    floatx4* __restrict__ out)
{
    int base = blockIdx.x * 1024 + threadIdx.x;

    // Issue all 8 independent loads before any use -> 8 outstanding
    // vmem ops per wave (vs 1-2 in round 1).
    floatx4 u0 = u[base];
    floatx4 u1 = u[base + 256];
    floatx4 u2 = u[base + 512];
    floatx4 u3 = u[base + 768];
    floatx4 i0 = img[base];
    floatx4 i1 = img[base + 256];
    floatx4 i2 = img[base + 512];
    floatx4 i3 = img[base + 768];

    floatx4 o0 = sp_select(u0, i0);
    floatx4 o1 = sp_select(u1, i1);
    floatx4 o2 = sp_select(u2, i2);
    floatx4 o3 = sp_select(u3, i3);

    // Output is write-once, never re-read: nontemporal to avoid evicting
    // the L3-resident input stream (FETCH_SIZE showed L3 absorbs ~1 input).
    __builtin_nontemporal_store(o0, &out[base]);
    __builtin_nontemporal_store(o1, &out[base + 256]);
    __builtin_nontemporal_store(o2, &out[base + 512]);
    __builtin_nontemporal_store(o3, &out[base + 768]);
}

// Remainder float4s (none for this problem shape; defensive).
__global__ __launch_bounds__(256) void saltpepper_f4_tail_kernel(
    const floatx4* __restrict__ img,
    const floatx4* __restrict__ u,
    floatx4* __restrict__ out,
    int start4, int n4)
{
    int i = start4 + blockIdx.x * blockDim.x + threadIdx.x;
    if (i < n4) {
        out[i] = sp_select(u[i], img[i]);
    }
}

// Remainder scalars (none for this problem shape; defensive).
__global__ __launch_bounds__(256) void saltpepper_scalar_tail_kernel(
    const float* __restrict__ img,
    const float* __restrict__ u,
    float* __restrict__ out,
    int start, int n)
{
    int i = start + blockIdx.x * blockDim.x + threadIdx.x;
    if (i < n) {
        float uv = u[i];
        out[i] = (uv < HALF_T) ? 0.0f : (uv < FULL_T) ? 1.0f : img[i];
    }
}

extern "C" void kernel_launch(void* const* d_in, const int* in_sizes, int n_in,
                              void* d_out, int out_size, void* d_ws, size_t ws_size,
                              hipStream_t stream) {
    const float* img = (const float*)d_in[0];
    const float* u   = (const float*)d_in[1];
    float* out = (float*)d_out;
    int n = in_sizes[0];

    int n4 = n / 4;              // whole float4s
    int nb = n4 / 1024;          // full 1024-float4 blocks
    int f4_done = nb * 1024;
    int sc_done = n4 * 4;

    if (nb > 0) {
        saltpepper_x4_kernel<<<nb, 256, 0, stream>>>(
            (const floatx4*)img, (const floatx4*)u, (floatx4*)out);
    }
    int f4_tail = n4 - f4_done;
    if (f4_tail > 0) {
        int g = (f4_tail + 255) / 256;
        saltpepper_f4_tail_kernel<<<g, 256, 0, stream>>>(
            (const floatx4*)img, (const floatx4*)u, (floatx4*)out, f4_done, n4);
    }
    int sc_tail = n - sc_done;
    if (sc_tail > 0) {
        int g = (sc_tail + 255) / 256;
        saltpepper_scalar_tail_kernel<<<g, 256, 0, stream>>>(
            img, u, out, sc_done, n);
    }
}